// Round 10
// baseline (85.938 us; speedup 1.0000x reference)
//
#include <hip/hip_runtime.h>

// Contrast-depth loss:
//   d = out - label   (elementwise, [B,32,32] fp32)
//   loss = mean over (b, 8 neighbors, 30x30 centers) of
//          (d[y+dy][x+dx] - d[y][x])^2, centers y,x in [1,30]
//
// R10 design: R8's proven per-thread 6x6-center tile (exact 32x32 tiling, no
// masks/LDS/barriers in hot path) + R4-PROVEN fused last-block reduction:
// counter zeroed by hipMemsetAsync each launch, winner = 1600th incrementer
// (old == nblocks-1), threadfence + fixed-order sum -> deterministic.
// (R9's never-reset mod-counter was wrong: with nonzero start the winner
// fires before all partials are written.)

#define THREADS 256

__global__ __launch_bounds__(THREADS, 2) void cdl_fused(
    const float* __restrict__ outp,
    const float* __restrict__ labp,
    float* __restrict__ partial,
    int* __restrict__ counter,      // memset to 0 before launch (in-graph)
    float* __restrict__ out,
    int nimg, int nblocks, float inv_count)
{
    const int t  = threadIdx.x;
    const int tg = blockIdx.x * THREADS + t;
    const int img = tg / 25;                    // 25 tiles per image
    const int tau = tg - img * 25;
    const int ty = tau / 5, tx = tau - ty * 5;

    float a0 = 0.f, a1 = 0.f, a2 = 0.f, a3 = 0.f;

    if (img < nimg) {
        // patch origin: row 6ty, col 6tx (6tx even -> float2-aligned)
        const long long fb = (long long)img * 1024 + (6 * ty) * 32 + 6 * tx;
        const float2* ob = (const float2*)(outp + fb);
        const float2* lb = (const float2*)(labp + fb);

        // ---- 64 independent 8B loads, immediate offsets off two bases ----
        float2 ov[8][4], lv[8][4];
        #pragma unroll
        for (int r = 0; r < 8; ++r) {
            #pragma unroll
            for (int c = 0; c < 4; ++c) ov[r][c] = ob[r * 16 + c];
        }
        #pragma unroll
        for (int r = 0; r < 8; ++r) {
            #pragma unroll
            for (int c = 0; c < 4; ++c) lv[r][c] = lb[r * 16 + c];
        }

        // ---- subtract into 8x8 patch ----
        float d[8][8];
        #pragma unroll
        for (int r = 0; r < 8; ++r) {
            #pragma unroll
            for (int c = 0; c < 4; ++c) {
                d[r][2 * c]     = ov[r][c].x - lv[r][c].x;
                d[r][2 * c + 1] = ov[r][c].y - lv[r][c].y;
            }
        }

        // ---- 6x6 centers, 8 neighbors each; 4 rotating accumulators ----
        #pragma unroll
        for (int cy = 1; cy <= 6; ++cy) {
            #pragma unroll
            for (int cx = 1; cx <= 6; ++cx) {
                const float c = d[cy][cx];
                float s = 0.f, v;
                v = d[cy - 1][cx - 1] - c; s += v * v;
                v = d[cy - 1][cx    ] - c; s += v * v;
                v = d[cy - 1][cx + 1] - c; s += v * v;
                v = d[cy    ][cx - 1] - c; s += v * v;
                v = d[cy    ][cx + 1] - c; s += v * v;
                v = d[cy + 1][cx - 1] - c; s += v * v;
                v = d[cy + 1][cx    ] - c; s += v * v;
                v = d[cy + 1][cx + 1] - c; s += v * v;
                const int k = (cy * 6 + cx) & 3;
                if (k == 0) a0 += s; else if (k == 1) a1 += s;
                else if (k == 2) a2 += s; else a3 += s;
            }
        }
    }

    float acc = (a0 + a1) + (a2 + a3);

    // ---- block reduction (fixed order, deterministic) ----
    #pragma unroll
    for (int off = 32; off; off >>= 1) acc += __shfl_down(acc, off, 64);
    __shared__ float red[4];
    const int lane = t & 63, wid = t >> 6;
    if (lane == 0) red[wid] = acc;
    __syncthreads();
    if (t == 0) {
        partial[blockIdx.x] = red[0] + red[1] + red[2] + red[3];
        __threadfence();
    }
    __syncthreads();

    // last arriving block (the nblocks-th incrementer) reduces all partials
    // in fixed order -> deterministic. Counter is zeroed every launch.
    __shared__ int is_last;
    if (t == 0) is_last = (atomicAdd(counter, 1) == nblocks - 1) ? 1 : 0;
    __syncthreads();
    if (is_last) {
        __threadfence();
        float a = 0.f;
        for (int i = t; i < nblocks; i += THREADS) a += partial[i];
        #pragma unroll
        for (int off = 32; off; off >>= 1) a += __shfl_down(a, off, 64);
        if (lane == 0) red[wid] = a;
        __syncthreads();
        if (t == 0) out[0] = (red[0] + red[1] + red[2] + red[3]) * inv_count;
    }
}

extern "C" void kernel_launch(void* const* d_in, const int* in_sizes, int n_in,
                              void* d_out, int out_size, void* d_ws, size_t ws_size,
                              hipStream_t stream) {
    const float* outp = (const float*)d_in[0];
    const float* labp = (const float*)d_in[1];
    const int nimg = in_sizes[0] / 1024;                        // B (H=W=32)
    const long long ntask = (long long)nimg * 25;
    const int nblocks = (int)((ntask + THREADS - 1) / THREADS); // 1600 for B=16384
    const float inv_count = 1.0f / ((float)nimg * 8.0f * 900.0f);

    int* counter = (int*)d_ws;                    // [0], zeroed each launch
    float* partial = (float*)d_ws + 64;           // [64 .. 64+nblocks)
    hipMemsetAsync(counter, 0, sizeof(int), stream);   // graph-capture-safe

    cdl_fused<<<nblocks, THREADS, 0, stream>>>(outp, labp, partial, counter,
                                               (float*)d_out, nimg, nblocks,
                                               inv_count);
}

// Round 11
// 39.033 us; speedup vs baseline: 2.2017x; 2.2017x over previous
//
#include <hip/hip_runtime.h>

// Contrast-depth loss:
//   d = out - label   (elementwise, [B,32,32] fp32)
//   loss = mean over (b, 8 neighbors, 30x30 centers) of
//          (d[y+dy][x+dx] - d[y][x])^2, centers y,x in [1,30]
//
// R11 design: R8's proven per-thread 6x6-center tile (exact 32x32 tiling,
// no masks/LDS/barriers in hot path), reduction via one device-scope
// atomicAdd(float) per block into d_out[0] (zeroed by a 4-byte memset node).
// NO __threadfence -- R4/R7/R10 showed per-block threadfence costs ~60-80us
// on MI355X (device fence over non-coherent per-XCD L2s serializes).
// Float-atomic ordering noise ~1e-6 on a loss of ~4 (threshold 8e-2).

#define THREADS 256

__global__ __launch_bounds__(THREADS, 2) void cdl_fused(
    const float* __restrict__ outp,
    const float* __restrict__ labp,
    float* __restrict__ out,
    int nimg, float inv_count)
{
    const int t  = threadIdx.x;
    const int tg = blockIdx.x * THREADS + t;
    const int img = tg / 25;                    // 25 tiles per image
    const int tau = tg - img * 25;
    const int ty = tau / 5, tx = tau - ty * 5;

    float a0 = 0.f, a1 = 0.f, a2 = 0.f, a3 = 0.f;

    if (img < nimg) {
        // patch origin: row 6ty, col 6tx (6tx even -> float2-aligned)
        const long long fb = (long long)img * 1024 + (6 * ty) * 32 + 6 * tx;
        const float2* ob = (const float2*)(outp + fb);
        const float2* lb = (const float2*)(labp + fb);

        // ---- 64 independent 8B loads, immediate offsets off two bases ----
        float2 ov[8][4], lv[8][4];
        #pragma unroll
        for (int r = 0; r < 8; ++r) {
            #pragma unroll
            for (int c = 0; c < 4; ++c) ov[r][c] = ob[r * 16 + c];
        }
        #pragma unroll
        for (int r = 0; r < 8; ++r) {
            #pragma unroll
            for (int c = 0; c < 4; ++c) lv[r][c] = lb[r * 16 + c];
        }

        // ---- subtract into 8x8 patch ----
        float d[8][8];
        #pragma unroll
        for (int r = 0; r < 8; ++r) {
            #pragma unroll
            for (int c = 0; c < 4; ++c) {
                d[r][2 * c]     = ov[r][c].x - lv[r][c].x;
                d[r][2 * c + 1] = ov[r][c].y - lv[r][c].y;
            }
        }

        // ---- 6x6 centers, 8 neighbors each; 4 rotating accumulators ----
        #pragma unroll
        for (int cy = 1; cy <= 6; ++cy) {
            #pragma unroll
            for (int cx = 1; cx <= 6; ++cx) {
                const float c = d[cy][cx];
                float s = 0.f, v;
                v = d[cy - 1][cx - 1] - c; s += v * v;
                v = d[cy - 1][cx    ] - c; s += v * v;
                v = d[cy - 1][cx + 1] - c; s += v * v;
                v = d[cy    ][cx - 1] - c; s += v * v;
                v = d[cy    ][cx + 1] - c; s += v * v;
                v = d[cy + 1][cx - 1] - c; s += v * v;
                v = d[cy + 1][cx    ] - c; s += v * v;
                v = d[cy + 1][cx + 1] - c; s += v * v;
                const int k = (cy * 6 + cx) & 3;
                if (k == 0) a0 += s; else if (k == 1) a1 += s;
                else if (k == 2) a2 += s; else a3 += s;
            }
        }
    }

    float acc = (a0 + a1) + (a2 + a3);

    // ---- block reduction (wave shuffle + LDS), then ONE atomic per block ----
    #pragma unroll
    for (int off = 32; off; off >>= 1) acc += __shfl_down(acc, off, 64);
    __shared__ float red[4];
    const int lane = t & 63, wid = t >> 6;
    if (lane == 0) red[wid] = acc;
    __syncthreads();
    if (t == 0) {
        const float bsum = red[0] + red[1] + red[2] + red[3];
        atomicAdd(out, bsum * inv_count);   // device-scope by default (G12/m20)
    }
}

extern "C" void kernel_launch(void* const* d_in, const int* in_sizes, int n_in,
                              void* d_out, int out_size, void* d_ws, size_t ws_size,
                              hipStream_t stream) {
    const float* outp = (const float*)d_in[0];
    const float* labp = (const float*)d_in[1];
    const int nimg = in_sizes[0] / 1024;                        // B (H=W=32)
    const long long ntask = (long long)nimg * 25;
    const int nblocks = (int)((ntask + THREADS - 1) / THREADS); // 1600 for B=16384
    const float inv_count = 1.0f / ((float)nimg * 8.0f * 900.0f);

    hipMemsetAsync(d_out, 0, sizeof(float), stream);   // graph-capture-safe

    cdl_fused<<<nblocks, THREADS, 0, stream>>>(outp, labp, (float*)d_out,
                                               nimg, inv_count);
}